// Round 1
// baseline (393.594 us; speedup 1.0000x reference)
//
#include <hip/hip_runtime.h>

// AlignmentMatrix: out[b,i,j] = sum_d body[b,i,d]*w3[d]*pun[b,j,d]
//                             + dot(body[b,i,:],w1) + dot(pun[b,j,:],w2)
// B=64, L=1024, D=128, fp32 in/out.
//
// R3: precompute bf16 hi/lo split (with w3 folded into body) in the pre-pass,
// stage via global_load_lds width=16 (no conversion VALU / ds_write in the
// main loop), launch_bounds(512,4) for 2 blocks/CU.
// Rank-1 terms computed in the same pre-pass (fp32, same math as before).

#define LSEQ 1024
#define H2K  128

// ws layout (float index / short index from short base):
//   ws[0      .. 65536)   s_body (fp32)
//   ws[65536  .. 131072)  s_pun  (fp32)
//   shorts at ws+131072:
//     [0        ..  8388608)  A_hi  (body*w3, bf16 hi)
//     [8388608  .. 16777216)  A_lo
//     [16777216 .. 25165824)  B_hi  (pun, bf16 hi)
//     [25165824 .. 33554432)  B_lo
// total = 512 KB + 64 MB  (ws observed >= 1 GiB)

typedef __attribute__((ext_vector_type(8))) short bfrag;
typedef __attribute__((ext_vector_type(4))) float f32x4;

__device__ __forceinline__ short f2bf(float x) {
    unsigned u = __float_as_uint(x);
    unsigned r = (u + 0x7fff + ((u >> 16) & 1)) >> 16;   // RNE
    return (short)r;
}
__device__ __forceinline__ float bf2f(short s) {
    return __uint_as_float(((unsigned)(unsigned short)s) << 16);
}

__device__ __forceinline__ void ld16(void* lds, const void* g) {
    __builtin_amdgcn_global_load_lds(
        (const __attribute__((address_space(1))) void*)g,
        (__attribute__((address_space(3))) void*)lds, 16, 0, 0);
}

// --- pre-pass: one wave per row. Computes rank-1 dot (fp32) and writes the
// bf16 hi/lo split of the cross-term operand (body*w3 or pun) row-major.
__global__ __launch_bounds__(256) void prep_kernel(
    const float* __restrict__ body, const float* __restrict__ pun,
    const float* __restrict__ w_u, float* __restrict__ ws)
{
    const int flag = blockIdx.y;                   // 0=body, 1=pun
    const int lane = threadIdx.x & 63;
    const int wv   = threadIdx.x >> 6;
    const size_t row = (size_t)blockIdx.x * 4 + wv;        // [0, B*LSEQ)

    const float* src = (flag ? pun : body) + row * H2K;
    const float2 v  = *(const float2*)(src + lane * 2);
    const float2 wm = *(const float2*)(w_u + flag * H2K + lane * 2);

    // fp32 rank-1 dot, full-wave butterfly reduce
    float p = v.x * wm.x + v.y * wm.y;
    p += __shfl_xor(p, 32);
    p += __shfl_xor(p, 16);
    p += __shfl_xor(p, 8);
    p += __shfl_xor(p, 4);
    p += __shfl_xor(p, 2);
    p += __shfl_xor(p, 1);
    if (lane == 0) ws[(size_t)flag * 65536 + row] = p;

    // cross-term operand: body gets w3 folded in, pun is raw
    float cx = v.x, cy = v.y;
    if (!flag) {
        const float2 w3v = *(const float2*)(w_u + 2 * H2K + lane * 2);
        cx *= w3v.x; cy *= w3v.y;
    }
    const short h0 = f2bf(cx), h1 = f2bf(cy);
    const short l0 = f2bf(cx - bf2f(h0)), l1 = f2bf(cy - bf2f(h1));

    short* hb = (short*)(ws + 131072) + (size_t)flag * 16777216 + row * H2K + lane * 2;
    *(unsigned*)hb =
        ((unsigned)(unsigned short)h0) | ((unsigned)(unsigned short)h1 << 16);
    *(unsigned*)(hb + 8388608) =
        ((unsigned)(unsigned short)l0) | ((unsigned)(unsigned short)l1 << 16);
}

// --- main kernel: 128x128 tile / 512 threads, K chunked 4x32.
// Staging is 4x global_load_lds(16B) per thread per chunk, LDS in fragment
// order (dest byte = t*16, linear in lane order as required).
__global__ __launch_bounds__(512, 4) void align_mfma(
    const float* __restrict__ ws, float* __restrict__ out)
{
    __shared__ __align__(16) short Ah[4096], Al[4096], Bh[4096], Bl[4096]; // 32 KB

    const int bb = blockIdx.z;
    const int ti = blockIdx.y * 128, tj = blockIdx.x * 128;
    const int t    = threadIdx.x;
    const int lane = t & 63;
    const int w    = t >> 6;                // wave id 0..7

    // Thread t owns fragment (mt = w, lane): row = w*16+(lane&15), k8 = lane>>4
    const int srow = w * 16 + (lane & 15);
    const int k8   = lane >> 4;

    const short* base = (const short*)(ws + 131072);
    const size_t arow = (size_t)(bb * LSEQ + ti + srow) * H2K + k8 * 8;
    const size_t brow = (size_t)(bb * LSEQ + tj + srow) * H2K + k8 * 8;
    const short* pAh = base + arow;
    const short* pAl = base + 8388608 + arow;
    const short* pBh = base + 16777216 + brow;
    const short* pBl = base + 25165824 + brow;

    short* dAh = &Ah[t * 8];
    short* dAl = &Al[t * 8];
    short* dBh = &Bh[t * 8];
    short* dBl = &Bl[t * 8];

    const int mt0 = (w >> 1) * 2;
    const int nt0 = (w & 1) * 4;
    f32x4 acc[2][4] = {};

    for (int kt = 0; kt < 4; ++kt) {
        if (kt) __syncthreads();           // LDS reuse guard

        // ---- stage chunk kt: 4 async 16B copies, no VGPR round-trip ----
        ld16(dAh, pAh + kt * 32);
        ld16(dAl, pAl + kt * 32);
        ld16(dBh, pBh + kt * 32);
        ld16(dBl, pBl + kt * 32);
        __syncthreads();                   // compiler drains vmcnt before barrier

        // ---- compute chunk kt: 24 MFMAs ----
        bfrag ah[2], al[2], bh[4], bl[4];
#pragma unroll
        for (int i = 0; i < 2; ++i) {
            ah[i] = *(const bfrag*)&Ah[((mt0 + i) * 64 + lane) * 8];
            al[i] = *(const bfrag*)&Al[((mt0 + i) * 64 + lane) * 8];
        }
#pragma unroll
        for (int j = 0; j < 4; ++j) {
            bh[j] = *(const bfrag*)&Bh[((nt0 + j) * 64 + lane) * 8];
            bl[j] = *(const bfrag*)&Bl[((nt0 + j) * 64 + lane) * 8];
        }
#pragma unroll
        for (int i = 0; i < 2; ++i)
#pragma unroll
            for (int j = 0; j < 4; ++j) {
                acc[i][j] = __builtin_amdgcn_mfma_f32_16x16x32_bf16(ah[i], bh[j], acc[i][j], 0, 0, 0);
                acc[i][j] = __builtin_amdgcn_mfma_f32_16x16x32_bf16(ah[i], bl[j], acc[i][j], 0, 0, 0);
                acc[i][j] = __builtin_amdgcn_mfma_f32_16x16x32_bf16(al[i], bh[j], acc[i][j], 0, 0, 0);
            }
    }

    // ---- epilogue: + s_body[i] + s_pun[j], store ----
    const float* sbp = ws + (size_t)bb * LSEQ;            // index by local i
    const float* spp = ws + 65536 + (size_t)bb * LSEQ;    // index by local j
    const int quad = lane >> 4, ln = lane & 15;
#pragma unroll
    for (int i = 0; i < 2; ++i) {
        const int rbase = ti + (mt0 + i) * 16 + quad * 4;  // local row of reg 0
#pragma unroll
        for (int j = 0; j < 4; ++j) {
            const int col = tj + (nt0 + j) * 16 + ln;
            const float spv = spp[col];
#pragma unroll
            for (int v = 0; v < 4; ++v) {
                const int row = rbase + v;
                out[((size_t)bb * LSEQ + row) * LSEQ + col] = acc[i][j][v] + sbp[row] + spv;
            }
        }
    }
}

extern "C" void kernel_launch(void* const* d_in, const int* in_sizes, int n_in,
                              void* d_out, int out_size, void* d_ws, size_t ws_size,
                              hipStream_t stream) {
    const float* body = (const float*)d_in[1];
    const float* pun  = (const float*)d_in[2];
    const float* w_u  = (const float*)d_in[3];
    float* out = (float*)d_out;
    float* ws  = (float*)d_ws;
    const int B = in_sizes[1] / (LSEQ * H2K);

    dim3 g1((B * LSEQ) / 4, 2, 1);
    prep_kernel<<<g1, 256, 0, stream>>>(body, pun, w_u, ws);

    dim3 g2(LSEQ / 128, LSEQ / 128, B);
    align_mfma<<<g2, 512, 0, stream>>>(ws, out);
}